// Round 6
// baseline (252.066 us; speedup 1.0000x reference)
//
#include <hip/hip_runtime.h>
#include <math.h>

#define NBATCH 4
#define TDIM 2048
#define DDIM 1024

typedef __attribute__((ext_vector_type(8))) short short8;       // 8 bf16 MFMA frag
typedef __attribute__((ext_vector_type(16))) float floatx16;    // 32x32 MFMA acc
typedef __attribute__((ext_vector_type(4))) unsigned short ushort4v;

__device__ __forceinline__ unsigned short f2bf(float f) {
  unsigned int u = __float_as_uint(f);
  u += 0x7fffu + ((u >> 16) & 1u);   // round-to-nearest-even
  return (unsigned short)(u >> 16);
}

// async 16B global -> LDS (HW places lane i at lds_base + i*16)
__device__ __forceinline__ void gload_lds16(const ushort* g, ushort* l) {
  __builtin_amdgcn_global_load_lds(
      (const __attribute__((address_space(1))) void*)g,
      (__attribute__((address_space(3))) void*)l, 16, 0, 0);
}

// ---------------------------------------------------------------------------
// MFMA GEMM core, BK=64, now on v_mfma_f32_32x32x16_bf16 (2382 TF ceiling vs
// 2075 for 16x16x32; half the MFMA instruction count for the same FLOPs).
// C[128x128] block, NT: C[m][n] += sum_k A[m][k]*B[n][k], bf16 K-contiguous.
// 4 waves; wave (wm,wn) owns a 64x64 quadrant as 2x2 tiles of 32x32.
//
// LDS: As/Bs [128 rows][64 k] bf16, XOR-8 16B-chunk swizzle (slot = c^(row&7))
// — identical staging to R3/R5 (global_load_lds-compatible, no padding).
// Fragment reads: lane holds A[m=lane&31][k = kg*16 + (lane>>5)*8 + j], i.e.
// chunk c = 2*kg + (lane>>5) of row (quad base + lane&31); slot = c ^ (lane&7).
// Conflict check: per ds_read_b128, rows spread slots over all 8 positions,
// 2 lanes/bank = free (m136).
// ---------------------------------------------------------------------------
__device__ __forceinline__ void mfma_gemm_core(
    const ushort* __restrict__ Abase, const ushort* __restrict__ Bbase,
    int lda, int ldb, int K, ushort* As, ushort* Bs, floatx16 acc[2][2]) {
  const int tid = threadIdx.x;
  const int wave = tid >> 6;
  const int lane = tid & 63;
  const int l31 = lane & 31;
  const int h = lane >> 5;
  const int l7 = lane & 7;
  const int wm = wave >> 1, wn = wave & 1;

  // staging: wave stages rows [32*wave, 32*wave+32) of A and B (unchanged)
  const int srow = wave * 32 + (lane >> 3);
  const int schunk = (lane & 7) ^ ((lane >> 3) & 7);
  const ushort* ag = Abase + (size_t)srow * lda + schunk * 8;
  const ushort* bg = Bbase + (size_t)srow * ldb + schunk * 8;
  ushort* al = As + wave * 32 * 64;
  ushort* bl = Bs + wave * 32 * 64;

  const int arow0 = (wm * 64 + l31) * 64;
  const int brow0 = (wn * 64 + l31) * 64;

  for (int kt = 0; kt < K; kt += 64) {
#pragma unroll
    for (int i = 0; i < 4; ++i) {
      gload_lds16(ag + kt + (size_t)(8 * i) * lda, al + 8 * i * 64);
      gload_lds16(bg + kt + (size_t)(8 * i) * ldb, bl + 8 * i * 64);
    }
    __syncthreads();
#pragma unroll
    for (int kg = 0; kg < 4; ++kg) {
      const int so = ((2 * kg + h) ^ l7) * 8;
      short8 a0 = *(const short8*)&As[arow0 + so];
      short8 a1 = *(const short8*)&As[arow0 + 2048 + so];  // +32 rows
      short8 b0 = *(const short8*)&Bs[brow0 + so];
      short8 b1 = *(const short8*)&Bs[brow0 + 2048 + so];
      acc[0][0] = __builtin_amdgcn_mfma_f32_32x32x16_bf16(a0, b0, acc[0][0], 0, 0, 0);
      acc[0][1] = __builtin_amdgcn_mfma_f32_32x32x16_bf16(a0, b1, acc[0][1], 0, 0, 0);
      acc[1][0] = __builtin_amdgcn_mfma_f32_32x32x16_bf16(a1, b0, acc[1][0], 0, 0, 0);
      acc[1][1] = __builtin_amdgcn_mfma_f32_32x32x16_bf16(a1, b1, acc[1][1], 0, 0, 0);
    }
    __syncthreads();
  }
}

// C/D layout (m74/m101-verified): col = lane&31 (B row), local row =
// (reg&3) + 8*(reg>>2) + 4*(lane>>5); reg groups of 4 are 4 consecutive rows.

// ---------------------------------------------------------------------------
// Fused converts: blocks [0,8192) convert x; [8192,11264) permute+convert W
// (row e -> (e%3)*1024 + e/3; q-rows pre-scaled by exact 1/32 = 1/sqrt(d)).
// ---------------------------------------------------------------------------
__global__ __launch_bounds__(256) void convert_xw(
    const float* __restrict__ x, const float* __restrict__ W,
    ushort* __restrict__ xb, ushort* __restrict__ wb) {
  const int bid = blockIdx.x;
  if (bid < 8192) {
    const size_t i = (size_t)bid * 256 + threadIdx.x;  // float4 index
    float4 v = reinterpret_cast<const float4*>(x)[i];
    ushort4v hh = {f2bf(v.x), f2bf(v.y), f2bf(v.z), f2bf(v.w)};
    reinterpret_cast<ushort4v*>(xb)[i] = hh;
  } else {
    const int e = bid - 8192;
    const int c = e % 3, ii = e / 3;
    const float scale = (c == 0) ? 0.03125f : 1.0f;
    const float4 v = reinterpret_cast<const float4*>(W + (size_t)e * DDIM)[threadIdx.x];
    ushort4v hh = {f2bf(v.x * scale), f2bf(v.y * scale), f2bf(v.z * scale),
                   f2bf(v.w * scale)};
    reinterpret_cast<ushort4v*>(wb + (size_t)(c * DDIM + ii) * DDIM)[threadIdx.x] = hh;
  }
}

// ---------------------------------------------------------------------------
// QKV: [8192 x 3072] = xb[8192x1024] * wb[3072x1024]^T.  wb rows permuted
// (q|k|v blocks).  q,k row-major; v transposed [b][d][t] for PV's NT.
// ---------------------------------------------------------------------------
__global__ __launch_bounds__(256, 3) void qkv_gemm(
    const ushort* __restrict__ xb, const ushort* __restrict__ wb,
    ushort* __restrict__ qb, ushort* __restrict__ kb, ushort* __restrict__ vt) {
  __shared__ __align__(16) ushort As[128 * 64];
  __shared__ __align__(16) ushort Bs[128 * 64];
  const int m0 = blockIdx.y * 128;
  const int n0 = blockIdx.x * 128;
  floatx16 acc[2][2];
#pragma unroll
  for (int i = 0; i < 2; ++i)
#pragma unroll
    for (int j = 0; j < 2; ++j)
#pragma unroll
      for (int r = 0; r < 16; ++r) acc[i][j][r] = 0.f;

  mfma_gemm_core(xb + (size_t)m0 * DDIM, wb + (size_t)n0 * DDIM, DDIM, DDIM,
                 DDIM, As, Bs, acc);

  const int tid = threadIdx.x;
  const int wave = tid >> 6, lane = tid & 63;
  const int l31 = lane & 31, h = lane >> 5;
  const int wm = wave >> 1, wn = wave & 1;

  if (n0 < 2 * DDIM) {
    ushort* dst = (n0 < DDIM) ? qb : kb;
    const int cb = (n0 < DDIM) ? n0 : n0 - DDIM;
#pragma unroll
    for (int i = 0; i < 2; ++i)
#pragma unroll
      for (int j = 0; j < 2; ++j) {
        const int col = cb + wn * 64 + j * 32 + l31;
#pragma unroll
        for (int g = 0; g < 4; ++g) {
          const int rbase = m0 + wm * 64 + i * 32 + g * 8 + h * 4;
#pragma unroll
          for (int rr = 0; rr < 4; ++rr)
            dst[(size_t)(rbase + rr) * DDIM + col] = f2bf(acc[i][j][g * 4 + rr]);
        }
      }
  } else {
#pragma unroll
    for (int i = 0; i < 2; ++i)
#pragma unroll
      for (int g = 0; g < 4; ++g) {
        const int row = m0 + wm * 64 + i * 32 + g * 8 + h * 4;  // 4 consecutive t
        const int b = row >> 11, t = row & (TDIM - 1);
#pragma unroll
        for (int j = 0; j < 2; ++j) {
          const int d = (n0 - 2 * DDIM) + wn * 64 + j * 32 + l31;
          ushort4v pk = {f2bf(acc[i][j][g * 4 + 0]), f2bf(acc[i][j][g * 4 + 1]),
                         f2bf(acc[i][j][g * 4 + 2]), f2bf(acc[i][j][g * 4 + 3])};
          *reinterpret_cast<ushort4v*>(&vt[(size_t)((b << 10) + d) * TDIM + t]) = pk;
        }
      }
  }
}

// ---------------------------------------------------------------------------
// Score + exp + partial row sums (no max-subtract: scores ~N(0,.25), exp safe
// in fp32; softmax(x) = exp(x)/sum exactly).  Stores bf16 P_unnorm and per-row
// sums of this 128-col tile to lpart[(z*16 + nb)*2048 + row].
// ---------------------------------------------------------------------------
__global__ __launch_bounds__(256, 3) void score_gemm(
    const ushort* __restrict__ qb, const ushort* __restrict__ kb,
    ushort* __restrict__ Sb, float* __restrict__ lpart) {
  __shared__ __align__(16) ushort As[128 * 64];
  __shared__ __align__(16) ushort Bs[128 * 64];
  const int z = blockIdx.z;
  const int m0 = blockIdx.y * 128;
  const int n0 = blockIdx.x * 128;
  floatx16 acc[2][2];
#pragma unroll
  for (int i = 0; i < 2; ++i)
#pragma unroll
    for (int j = 0; j < 2; ++j)
#pragma unroll
      for (int r = 0; r < 16; ++r) acc[i][j][r] = 0.f;

  mfma_gemm_core(qb + ((size_t)z * TDIM + m0) * DDIM,
                 kb + ((size_t)z * TDIM + n0) * DDIM, DDIM, DDIM, DDIM, As, Bs,
                 acc);

  const int tid = threadIdx.x;
  const int wave = tid >> 6, lane = tid & 63;
  const int l31 = lane & 31, h = lane >> 5;
  const int wm = wave >> 1, wn = wave & 1;

#pragma unroll
  for (int i = 0; i < 2; ++i)
#pragma unroll
    for (int j = 0; j < 2; ++j)
#pragma unroll
      for (int r = 0; r < 16; ++r) acc[i][j][r] = __expf(acc[i][j][r]);

  ushort* S = Sb + (size_t)z * TDIM * TDIM;
#pragma unroll
  for (int i = 0; i < 2; ++i)
#pragma unroll
    for (int j = 0; j < 2; ++j) {
      const int col = n0 + wn * 64 + j * 32 + l31;
#pragma unroll
      for (int g = 0; g < 4; ++g) {
        const int rbase = m0 + wm * 64 + i * 32 + g * 8 + h * 4;
#pragma unroll
        for (int rr = 0; rr < 4; ++rr)
          S[(size_t)(rbase + rr) * TDIM + col] = f2bf(acc[i][j][g * 4 + rr]);
      }
    }

  // per-row tile sums: reduce over the 2 j-tiles, then across the 32-lane
  // half-wave (cols l31); lanes l31==0 (h=0 and h=1 cover disjoint rows).
  float* sums = reinterpret_cast<float*>(As);  // [128][2], As free after core
#pragma unroll
  for (int i = 0; i < 2; ++i)
#pragma unroll
    for (int reg = 0; reg < 16; ++reg) {
      float s = acc[i][0][reg] + acc[i][1][reg];
#pragma unroll
      for (int off = 16; off > 0; off >>= 1) s += __shfl_down(s, off, 32);
      if (l31 == 0)
        sums[(wm * 64 + i * 32 + (reg & 3) + 8 * (reg >> 2) + 4 * h) * 2 + wn] = s;
    }
  __syncthreads();
  if (tid < 128)
    lpart[((size_t)z * 16 + blockIdx.x) * TDIM + m0 + tid] =
        sums[tid * 2] + sums[tid * 2 + 1];
}

// ---------------------------------------------------------------------------
// PV + normalization: out[t][d] = (sum_j P_unnorm[t][j]*vt[d][j]) / l[t].
// ---------------------------------------------------------------------------
__global__ __launch_bounds__(256, 3) void pv_gemm(
    const ushort* __restrict__ Pb, const ushort* __restrict__ vt,
    const float* __restrict__ lpart, float* __restrict__ out) {
  __shared__ __align__(16) ushort As[128 * 64];
  __shared__ __align__(16) ushort Bs[128 * 64];
  const int z = blockIdx.z;
  const int m0 = blockIdx.y * 128;
  const int n0 = blockIdx.x * 128;
  floatx16 acc[2][2];
#pragma unroll
  for (int i = 0; i < 2; ++i)
#pragma unroll
    for (int j = 0; j < 2; ++j)
#pragma unroll
      for (int r = 0; r < 16; ++r) acc[i][j][r] = 0.f;

  mfma_gemm_core(Pb + (size_t)z * TDIM * TDIM + (size_t)m0 * TDIM,
                 vt + (size_t)z * DDIM * TDIM + (size_t)n0 * TDIM, TDIM, TDIM,
                 TDIM, As, Bs, acc);

  const int tid = threadIdx.x;
  const int wave = tid >> 6, lane = tid & 63;
  const int l31 = lane & 31, h = lane >> 5;
  const int wm = wave >> 1, wn = wave & 1;

  // row normalizers: sum 16 partials per row, reciprocal into LDS
  float* linv = reinterpret_cast<float*>(As);  // [128], As free after core
  if (tid < 128) {
    float s = 0.f;
#pragma unroll
    for (int nb = 0; nb < 16; ++nb)
      s += lpart[((size_t)z * 16 + nb) * TDIM + m0 + tid];
    linv[tid] = 1.0f / s;
  }
  __syncthreads();

  float* O = out + (size_t)z * TDIM * DDIM;
#pragma unroll
  for (int i = 0; i < 2; ++i)
#pragma unroll
    for (int g = 0; g < 4; ++g) {
      const int rl = wm * 64 + i * 32 + g * 8 + h * 4;
      float sc[4];
#pragma unroll
      for (int rr = 0; rr < 4; ++rr) sc[rr] = linv[rl + rr];
#pragma unroll
      for (int j = 0; j < 2; ++j) {
        const int col = n0 + wn * 64 + j * 32 + l31;
#pragma unroll
        for (int rr = 0; rr < 4; ++rr)
          O[(size_t)(m0 + rl + rr) * DDIM + col] = acc[i][j][g * 4 + rr] * sc[rr];
      }
    }
}

// ---------------------------------------------------------------------------
extern "C" void kernel_launch(void* const* d_in, const int* in_sizes, int n_in,
                              void* d_out, int out_size, void* d_ws, size_t ws_size,
                              hipStream_t stream) {
  const float* x = (const float*)d_in[0];  // [4,2048,1024] fp32
  const float* W = (const float*)d_in[1];  // [3072,1024] fp32
  float* out = (float*)d_out;              // [4,2048,1024] fp32

  ushort* ws = (ushort*)d_ws;
  const size_t n_x = (size_t)NBATCH * TDIM * DDIM;  // 8.39M
  const size_t n_w = (size_t)3 * DDIM * DDIM;       // 3.15M
  ushort* xb = ws;        // 16.8 MB
  ushort* wb = xb + n_x;  // 6.3 MB (rows permuted q|k|v, q pre-scaled 1/32)
  ushort* qb = wb + n_w;  // 16.8 MB [b*t][d]
  ushort* kb = qb + n_x;  // 16.8 MB [b*t][d]
  ushort* vt = kb + n_x;  // 16.8 MB [b][d][t]
  ushort* Sb = vt + n_x;  // 33.5 MB [b][t][t] bf16 unnormalized exp(scores)
  float* lpart = (float*)(Sb + (size_t)NBATCH * TDIM * TDIM);  // 512 KB

  convert_xw<<<dim3(8192 + 3 * DDIM), 256, 0, stream>>>(x, W, xb, wb);
  qkv_gemm<<<dim3(3 * DDIM / 128, NBATCH * TDIM / 128), 256, 0, stream>>>(
      xb, wb, qb, kb, vt);
  score_gemm<<<dim3(TDIM / 128, TDIM / 128, NBATCH), 256, 0, stream>>>(qb, kb,
                                                                       Sb, lpart);
  pv_gemm<<<dim3(DDIM / 128, TDIM / 128, NBATCH), 256, 0, stream>>>(Sb, vt,
                                                                    lpart, out);
}

// Round 7
// 229.664 us; speedup vs baseline: 1.0975x; 1.0975x over previous
//
#include <hip/hip_runtime.h>
#include <math.h>

#define NBATCH 4
#define TDIM 2048
#define DDIM 1024

typedef __attribute__((ext_vector_type(8))) short short8;     // 8 bf16 MFMA frag
typedef __attribute__((ext_vector_type(4))) float floatx4;    // MFMA acc
typedef __attribute__((ext_vector_type(8))) unsigned short ushort8;
typedef __attribute__((ext_vector_type(4))) unsigned short ushort4v;

__device__ __forceinline__ unsigned short f2bf(float f) {
  unsigned int u = __float_as_uint(f);
  u += 0x7fffu + ((u >> 16) & 1u);   // round-to-nearest-even
  return (unsigned short)(u >> 16);
}

// async 16B global -> LDS (HW places lane i at lds_base + i*16)
__device__ __forceinline__ void gload_lds16(const ushort* g, ushort* l) {
  __builtin_amdgcn_global_load_lds(
      (const __attribute__((address_space(1))) void*)g,
      (__attribute__((address_space(3))) void*)l, 16, 0, 0);
}

// ---------------------------------------------------------------------------
// MFMA GEMM core, BK=64 (R3/R5-proven: conflict-free XOR-8 swizzle, 873 TF;
// NOTE R6 showed the 32x32 MFMA variant of this layout re-introduces 6.3e6
// bank conflicts and regresses — keep 16x16x32).
// C[128x128] block, NT: C[m][n] += sum_k A[m][k]*B[n][k], bf16 K-contiguous.
// 4 waves; wave (wm,wn) owns a 64x64 quadrant as 4x4 mfma_f32_16x16x32_bf16.
// ---------------------------------------------------------------------------
__device__ __forceinline__ void mfma_gemm_core(
    const ushort* __restrict__ Abase, const ushort* __restrict__ Bbase,
    int lda, int ldb, int K, ushort* As, ushort* Bs, floatx4 acc[4][4]) {
  const int tid = threadIdx.x;
  const int wave = tid >> 6;
  const int lane = tid & 63;
  const int l15 = lane & 15;
  const int quad = lane >> 4;
  const int wm = wave >> 1, wn = wave & 1;

  const int srow = wave * 32 + (lane >> 3);
  const int schunk = (lane & 7) ^ ((lane >> 3) & 7);
  const ushort* ag = Abase + (size_t)srow * lda + schunk * 8;
  const ushort* bg = Bbase + (size_t)srow * ldb + schunk * 8;
  ushort* al = As + wave * 32 * 64;
  ushort* bl = Bs + wave * 32 * 64;

  const int slot = quad ^ (l15 & 7);
  const int abase = (wm * 64 + l15) * 64 + slot * 8;
  const int bbase = (wn * 64 + l15) * 64 + slot * 8;

  for (int kt = 0; kt < K; kt += 64) {
#pragma unroll
    for (int i = 0; i < 4; ++i) {
      gload_lds16(ag + kt + (size_t)(8 * i) * lda, al + 8 * i * 64);
      gload_lds16(bg + kt + (size_t)(8 * i) * ldb, bl + 8 * i * 64);
    }
    __syncthreads();
#pragma unroll
    for (int g = 0; g < 2; ++g) {
      const int ab = abase ^ (g * 32);
      const int bb = bbase ^ (g * 32);
      short8 af[4], bfr[4];
#pragma unroll
      for (int t = 0; t < 4; ++t) {
        af[t] = *(const short8*)&As[ab + t * 1024];
        bfr[t] = *(const short8*)&Bs[bb + t * 1024];
      }
#pragma unroll
      for (int i = 0; i < 4; ++i)
#pragma unroll
        for (int j = 0; j < 4; ++j)
          acc[i][j] =
              __builtin_amdgcn_mfma_f32_16x16x32_bf16(af[i], bfr[j], acc[i][j], 0, 0, 0);
    }
    __syncthreads();
  }
}

// ---------------------------------------------------------------------------
// Fused converts: blocks [0,8192) convert x; [8192,11264) permute+convert W
// (row e -> (e%3)*1024 + e/3; q-rows pre-scaled by exact 1/32 = 1/sqrt(d)).
// ---------------------------------------------------------------------------
__global__ __launch_bounds__(256) void convert_xw(
    const float* __restrict__ x, const float* __restrict__ W,
    ushort* __restrict__ xb, ushort* __restrict__ wb) {
  const int bid = blockIdx.x;
  if (bid < 8192) {
    const size_t i = (size_t)bid * 256 + threadIdx.x;  // float4 index
    float4 v = reinterpret_cast<const float4*>(x)[i];
    ushort4v h = {f2bf(v.x), f2bf(v.y), f2bf(v.z), f2bf(v.w)};
    reinterpret_cast<ushort4v*>(xb)[i] = h;
  } else {
    const int e = bid - 8192;
    const int c = e % 3, ii = e / 3;
    const float scale = (c == 0) ? 0.03125f : 1.0f;
    const float4 v = reinterpret_cast<const float4*>(W + (size_t)e * DDIM)[threadIdx.x];
    ushort4v h = {f2bf(v.x * scale), f2bf(v.y * scale), f2bf(v.z * scale),
                  f2bf(v.w * scale)};
    reinterpret_cast<ushort4v*>(wb + (size_t)(c * DDIM + ii) * DDIM)[threadIdx.x] = h;
  }
}

// ---------------------------------------------------------------------------
// QKV: [8192 x 3072] = xb[8192x1024] * wb[3072x1024]^T.  wb rows permuted
// (q|k|v blocks).  q,k row-major; v transposed [b][d][t] for PV's NT.
// ---------------------------------------------------------------------------
__global__ __launch_bounds__(256, 3) void qkv_gemm(
    const ushort* __restrict__ xb, const ushort* __restrict__ wb,
    ushort* __restrict__ qb, ushort* __restrict__ kb, ushort* __restrict__ vt) {
  __shared__ __align__(16) ushort As[128 * 64];
  __shared__ __align__(16) ushort Bs[128 * 64];
  const int m0 = blockIdx.y * 128;
  const int n0 = blockIdx.x * 128;
  floatx4 acc[4][4];
  const floatx4 z4 = {0.f, 0.f, 0.f, 0.f};
#pragma unroll
  for (int i = 0; i < 4; ++i)
#pragma unroll
    for (int j = 0; j < 4; ++j) acc[i][j] = z4;

  mfma_gemm_core(xb + (size_t)m0 * DDIM, wb + (size_t)n0 * DDIM, DDIM, DDIM,
                 DDIM, As, Bs, acc);

  const int tid = threadIdx.x;
  const int wave = tid >> 6, lane = tid & 63;
  const int l15 = lane & 15, quad = lane >> 4;
  const int wm = wave >> 1, wn = wave & 1;

  if (n0 < 2 * DDIM) {
    ushort* dst = (n0 < DDIM) ? qb : kb;
    const int cb = (n0 < DDIM) ? n0 : n0 - DDIM;
#pragma unroll
    for (int i = 0; i < 4; ++i) {
      const int rbase = m0 + wm * 64 + i * 16 + quad * 4;
#pragma unroll
      for (int j = 0; j < 4; ++j) {
        const int col = cb + wn * 64 + j * 16 + l15;
#pragma unroll
        for (int r = 0; r < 4; ++r)
          dst[(size_t)(rbase + r) * DDIM + col] = f2bf(acc[i][j][r]);
      }
    }
  } else {
#pragma unroll
    for (int i = 0; i < 4; ++i) {
      const int row = m0 + wm * 64 + i * 16 + quad * 4;  // 4 consecutive t
      const int b = row >> 11, t = row & (TDIM - 1);
#pragma unroll
      for (int j = 0; j < 4; ++j) {
        const int d = (n0 - 2 * DDIM) + wn * 64 + j * 16 + l15;
        ushort4v pk = {f2bf(acc[i][j][0]), f2bf(acc[i][j][1]),
                       f2bf(acc[i][j][2]), f2bf(acc[i][j][3])};
        *reinterpret_cast<ushort4v*>(&vt[(size_t)((b << 10) + d) * TDIM + t]) = pk;
      }
    }
  }
}

// ---------------------------------------------------------------------------
// Score + exp + partial row sums.  S tile (z, m0, n0):
//   P_unnorm[i][j] = exp(q_scaled[i]·k[j])   (no max-subtract: scores ~N(0,.25),
//   row max ~3, exp safe in fp32; softmax(x) = exp(x)/sum exactly)
// Stores P_unnorm bf16, and per-row sums of this 128-col tile to
// lpart[(z*16 + nb) * 2048 + row].  pv_gemm divides by the total later.
// ---------------------------------------------------------------------------
__global__ __launch_bounds__(256, 3) void score_gemm(
    const ushort* __restrict__ qb, const ushort* __restrict__ kb,
    ushort* __restrict__ Sb, float* __restrict__ lpart) {
  __shared__ __align__(16) ushort As[128 * 64];
  __shared__ __align__(16) ushort Bs[128 * 64];
  const int z = blockIdx.z;
  const int m0 = blockIdx.y * 128;
  const int n0 = blockIdx.x * 128;
  floatx4 acc[4][4];
  const floatx4 z4 = {0.f, 0.f, 0.f, 0.f};
#pragma unroll
  for (int i = 0; i < 4; ++i)
#pragma unroll
    for (int j = 0; j < 4; ++j) acc[i][j] = z4;

  mfma_gemm_core(qb + ((size_t)z * TDIM + m0) * DDIM,
                 kb + ((size_t)z * TDIM + n0) * DDIM, DDIM, DDIM, DDIM, As, Bs,
                 acc);

  const int tid = threadIdx.x;
  const int wave = tid >> 6, lane = tid & 63;
  const int l15 = lane & 15, quad = lane >> 4;
  const int wm = wave >> 1, wn = wave & 1;

  // exponentiate in fp32, store bf16 P_unnorm
  ushort* S = Sb + (size_t)z * TDIM * TDIM;
#pragma unroll
  for (int i = 0; i < 4; ++i)
#pragma unroll
    for (int j = 0; j < 4; ++j)
#pragma unroll
      for (int r = 0; r < 4; ++r) acc[i][j][r] = __expf(acc[i][j][r]);

#pragma unroll
  for (int i = 0; i < 4; ++i) {
    const int rbase = m0 + wm * 64 + i * 16 + quad * 4;
#pragma unroll
    for (int j = 0; j < 4; ++j) {
      const int col = n0 + wn * 64 + j * 16 + l15;
#pragma unroll
      for (int r = 0; r < 4; ++r)
        S[(size_t)(rbase + r) * TDIM + col] = f2bf(acc[i][j][r]);
    }
  }

  // per-row sums of this tile: reduce over j then over the 16-lane quad group
  float* sums = reinterpret_cast<float*>(As);  // [128][2], As free after core
  __syncthreads();  // ensure all LDS reads of the core are done on all waves
#pragma unroll
  for (int i = 0; i < 4; ++i) {
#pragma unroll
    for (int r = 0; r < 4; ++r) {
      float s = acc[i][0][r] + acc[i][1][r] + acc[i][2][r] + acc[i][3][r];
#pragma unroll
      for (int off = 8; off > 0; off >>= 1) s += __shfl_down(s, off, 16);
      if (l15 == 0) sums[(wm * 64 + i * 16 + quad * 4 + r) * 2 + wn] = s;
    }
  }
  __syncthreads();
  if (tid < 128)
    lpart[((size_t)z * 16 + blockIdx.x) * TDIM + m0 + tid] =
        sums[tid * 2] + sums[tid * 2 + 1];
}

// ---------------------------------------------------------------------------
// PV + normalization: out[t][d] = (sum_j P_unnorm[t][j]*vt[d][j]) / l[t],
// l[t] = sum over the 16 score-tile partials.
// ---------------------------------------------------------------------------
__global__ __launch_bounds__(256, 3) void pv_gemm(
    const ushort* __restrict__ Pb, const ushort* __restrict__ vt,
    const float* __restrict__ lpart, float* __restrict__ out) {
  __shared__ __align__(16) ushort As[128 * 64];
  __shared__ __align__(16) ushort Bs[128 * 64];
  const int z = blockIdx.z;
  const int m0 = blockIdx.y * 128;
  const int n0 = blockIdx.x * 128;
  floatx4 acc[4][4];
  const floatx4 z4 = {0.f, 0.f, 0.f, 0.f};
#pragma unroll
  for (int i = 0; i < 4; ++i)
#pragma unroll
    for (int j = 0; j < 4; ++j) acc[i][j] = z4;

  mfma_gemm_core(Pb + (size_t)z * TDIM * TDIM + (size_t)m0 * TDIM,
                 vt + (size_t)z * DDIM * TDIM + (size_t)n0 * TDIM, TDIM, TDIM,
                 TDIM, As, Bs, acc);

  const int tid = threadIdx.x;
  const int wave = tid >> 6, lane = tid & 63;
  const int l15 = lane & 15, quad = lane >> 4;
  const int wm = wave >> 1, wn = wave & 1;

  // row normalizers: sum 16 partials per row, reciprocal into LDS
  float* linv = reinterpret_cast<float*>(As);  // [128], As free after core
  __syncthreads();
  if (tid < 128) {
    float s = 0.f;
#pragma unroll
    for (int nb = 0; nb < 16; ++nb)
      s += lpart[((size_t)z * 16 + nb) * TDIM + m0 + tid];
    linv[tid] = 1.0f / s;
  }
  __syncthreads();

  float* O = out + (size_t)z * TDIM * DDIM;
#pragma unroll
  for (int i = 0; i < 4; ++i) {
    const int rl = wm * 64 + i * 16 + quad * 4;
    const int rbase = m0 + rl;
#pragma unroll
    for (int j = 0; j < 4; ++j) {
      const int col = n0 + wn * 64 + j * 16 + l15;
#pragma unroll
      for (int r = 0; r < 4; ++r)
        O[(size_t)(rbase + r) * DDIM + col] = acc[i][j][r] * linv[rl + r];
    }
  }
}

// ---------------------------------------------------------------------------
extern "C" void kernel_launch(void* const* d_in, const int* in_sizes, int n_in,
                              void* d_out, int out_size, void* d_ws, size_t ws_size,
                              hipStream_t stream) {
  const float* x = (const float*)d_in[0];  // [4,2048,1024] fp32
  const float* W = (const float*)d_in[1];  // [3072,1024] fp32
  float* out = (float*)d_out;              // [4,2048,1024] fp32

  ushort* ws = (ushort*)d_ws;
  const size_t n_x = (size_t)NBATCH * TDIM * DDIM;  // 8.39M
  const size_t n_w = (size_t)3 * DDIM * DDIM;       // 3.15M
  ushort* xb = ws;        // 16.8 MB
  ushort* wb = xb + n_x;  // 6.3 MB (rows permuted q|k|v, q pre-scaled 1/32)
  ushort* qb = wb + n_w;  // 16.8 MB [b*t][d]
  ushort* kb = qb + n_x;  // 16.8 MB [b*t][d]
  ushort* vt = kb + n_x;  // 16.8 MB [b][d][t]
  ushort* Sb = vt + n_x;  // 33.5 MB [b][t][t] bf16 unnormalized exp(scores)
  float* lpart = (float*)(Sb + (size_t)NBATCH * TDIM * TDIM);  // 512 KB

  convert_xw<<<dim3(8192 + 3 * DDIM), 256, 0, stream>>>(x, W, xb, wb);
  qkv_gemm<<<dim3(3 * DDIM / 128, NBATCH * TDIM / 128), 256, 0, stream>>>(
      xb, wb, qb, kb, vt);
  score_gemm<<<dim3(TDIM / 128, TDIM / 128, NBATCH), 256, 0, stream>>>(qb, kb,
                                                                       Sb, lpart);
  pv_gemm<<<dim3(DDIM / 128, TDIM / 128, NBATCH), 256, 0, stream>>>(Sb, vt,
                                                                    lpart, out);
}